// Round 1
// 336.113 us; speedup vs baseline: 1.3145x; 1.3145x over previous
//
#include <hip/hip_runtime.h>

#define N_NODES 100000
#define E_EDGES 600000
#define LATDIM 128
#define HEAD 4
#define HDIM 32

#define SCAN_CHUNK 1024
#define SCAN_NB ((N_NODES + SCAN_CHUNK - 1) / SCAN_CHUNK)   // 98

typedef __bf16 bf16x8 __attribute__((ext_vector_type(8)));
typedef float  f32x4  __attribute__((ext_vector_type(4)));

__device__ __forceinline__ unsigned f32_to_bf16_rne(float x) {
    unsigned u = __float_as_uint(x);
    u += 0x7fffu + ((u >> 16) & 1u);   // round to nearest even
    return u >> 16;
}

__device__ __forceinline__ void bf16_split(float x, unsigned& hi, unsigned& lo) {
    unsigned hb = f32_to_bf16_rne(x);
    float hf = __uint_as_float(hb << 16);
    unsigned lb = f32_to_bf16_rne(x - hf);
    hi = hb; lo = lb;
}

// ---------------------------------------------------------------------------
// Weight prep: W[k][c] f32 -> WT_hi/WT_lo[m][c][k] bf16 (split precision).
// 3*128*128 elems; 12 blocks x 256 thr, each thread does 16 contiguous k.
// ---------------------------------------------------------------------------
__global__ __launch_bounds__(256) void wprep_kernel(
    const float* __restrict__ qT, const float* __restrict__ kT,
    const float* __restrict__ vT,
    unsigned short* __restrict__ WThi, unsigned short* __restrict__ WTlo)
{
    int g = blockIdx.x * 256 + threadIdx.x;      // 0..3071
    if (g >= 3072) return;
    int m    = g >> 10;          // 0..2
    int rem  = g & 1023;
    int c    = rem >> 3;         // 0..127
    int k0   = (rem & 7) * 16;   // 0..112
    const float* W = (m == 0) ? qT : (m == 1) ? kT : vT;

    unsigned short hi[16], lo[16];
    #pragma unroll
    for (int j = 0; j < 16; ++j) {
        float x = W[(size_t)(k0 + j) * 128 + c];
        unsigned hb, lb;
        bf16_split(x, hb, lb);
        hi[j] = (unsigned short)hb;
        lo[j] = (unsigned short)lb;
    }
    size_t off = (size_t)m * 16384 + (size_t)c * 128 + k0;
    *(uint4*)(WThi + off)     = *(const uint4*)&hi[0];
    *(uint4*)(WThi + off + 8) = *(const uint4*)&hi[8];
    *(uint4*)(WTlo + off)     = *(const uint4*)&lo[0];
    *(uint4*)(WTlo + off + 8) = *(const uint4*)&lo[8];
}

// ---------------------------------------------------------------------------
// Kernel A (MFMA): fused per-node Q/K/V transform via 16x16x32 bf16 MFMA with
// split-precision (hi+lo) operands: a*b ~= ah*bh + al*bh + ah*bl  (fp32-level).
// Block: 256 thr (4 waves) = 64 node rows; each wave owns a 16-row tile.
// LDS (64 KiB): Ahi|Alo [64][128]bf16, Bhi|Blo [64 cols][128 k]bf16,
// all XOR-swizzled (byte ^= (row&7)<<4) to kill the 256B-stride ds_read_b128
// bank conflict (guide G4/T2).
// ---------------------------------------------------------------------------
__global__ __launch_bounds__(256, 2) void qkv_mfma_kernel(
    const float* __restrict__ embeds,
    const unsigned short* __restrict__ WThi,
    const unsigned short* __restrict__ WTlo,
    float* __restrict__ Q, unsigned* __restrict__ KV)
{
    __shared__ __align__(16) char smem[65536];
    char* Ahi = smem;              // 16 KiB: 64 rows x 256B
    char* Alo = smem + 16384;
    char* Bhi = smem + 32768;      // 16 KiB: 64 cols x 256B
    char* Blo = smem + 49152;

    const int tid = threadIdx.x;
    const int rowBase = blockIdx.x * 64;

    // ---- stage A: load embeds f32, split to bf16 hi/lo, swizzled LDS ----
    #pragma unroll
    for (int it = 0; it < 8; ++it) {
        int idx = it * 256 + tid;          // 0..2047 float4 chunks
        int r  = idx >> 5;                 // 0..63
        int c4 = idx & 31;                 // 0..31
        int gr = rowBase + r;
        float4 v = make_float4(0.f, 0.f, 0.f, 0.f);
        if (gr < N_NODES) v = ((const float4*)embeds)[(size_t)gr * 32 + c4];
        unsigned hx, lx, hy, ly, hz, lz, hw, lw;
        bf16_split(v.x, hx, lx); bf16_split(v.y, hy, ly);
        bf16_split(v.z, hz, lz); bf16_split(v.w, hw, lw);
        uint2 hp = make_uint2(hx | (hy << 16), hz | (hw << 16));
        uint2 lp = make_uint2(lx | (ly << 16), lz | (lw << 16));
        int byte = r * 256 + c4 * 8;
        int swz  = byte ^ ((r & 7) << 4);
        *(uint2*)(Ahi + swz) = hp;
        *(uint2*)(Alo + swz) = lp;
    }
    __syncthreads();

    const int lane = tid & 63;
    const int wv   = tid >> 6;         // 0..3 (wave -> 16-row tile)
    const int lrow = lane & 15;
    const int kg   = lane >> 4;        // 0..3 (k-group of MFMA operand)
    const int arow = wv * 16 + lrow;   // 0..63

    // ---- hoisted A fragments (reused for all 6 (h,m) output panels) ----
    bf16x8 a_hi[4], a_lo[4];
    #pragma unroll
    for (int kk = 0; kk < 4; ++kk) {
        int byte = arow * 256 + kk * 64 + kg * 16;
        int swz  = byte ^ ((lrow & 7) << 4);     // (arow&7)==(lrow&7)
        a_hi[kk] = __builtin_bit_cast(bf16x8, *(const uint4*)(Ahi + swz));
        a_lo[kk] = __builtin_bit_cast(bf16x8, *(const uint4*)(Alo + swz));
    }

    const int orow = kg << 2;   // C/D row base within 16-row tile (m89 layout)

    for (int h = 0; h < 2; ++h) {          // column half: cols h*64..h*64+63
        f32x4 kreg[4];
        for (int m = 0; m < 3; ++m) {      // 0:Q 1:K 2:V
            __syncthreads();               // prev panel's B reads done
            // ---- stage B(m,h): 64 cols x 128 k, hi+lo, linear copy ----
            {
                const char* srch = (const char*)(WThi + (size_t)m * 16384 + (size_t)h * 8192);
                const char* srcl = (const char*)(WTlo + (size_t)m * 16384 + (size_t)h * 8192);
                #pragma unroll
                for (int it = 0; it < 4; ++it) {
                    int idx  = it * 256 + tid;         // 16B chunk id, 0..1023
                    int cl   = idx >> 4;               // col 0..63
                    int byte = idx * 16;               // == cl*256 + ch*16
                    int swz  = (cl * 256 + (idx & 15) * 16) ^ ((cl & 7) << 4);
                    *(uint4*)(Bhi + swz) = *(const uint4*)(srch + byte);
                    *(uint4*)(Blo + swz) = *(const uint4*)(srcl + byte);
                }
            }
            __syncthreads();

            f32x4 acc[4] = { {0.f,0.f,0.f,0.f}, {0.f,0.f,0.f,0.f},
                             {0.f,0.f,0.f,0.f}, {0.f,0.f,0.f,0.f} };
            #pragma unroll
            for (int kk = 0; kk < 4; ++kk) {
                #pragma unroll
                for (int n = 0; n < 4; ++n) {
                    int brow = n * 16 + lrow;
                    int byte = brow * 256 + kk * 64 + kg * 16;
                    int swz  = byte ^ ((lrow & 7) << 4);   // (brow&7)==(lrow&7)
                    bf16x8 bh = __builtin_bit_cast(bf16x8, *(const uint4*)(Bhi + swz));
                    bf16x8 bl = __builtin_bit_cast(bf16x8, *(const uint4*)(Blo + swz));
                    acc[n] = __builtin_amdgcn_mfma_f32_16x16x32_bf16(a_hi[kk], bh, acc[n], 0, 0, 0);
                    acc[n] = __builtin_amdgcn_mfma_f32_16x16x32_bf16(a_lo[kk], bh, acc[n], 0, 0, 0);
                    acc[n] = __builtin_amdgcn_mfma_f32_16x16x32_bf16(a_hi[kk], bl, acc[n], 0, 0, 0);
                }
            }

            if (m == 0) {
                #pragma unroll
                for (int n = 0; n < 4; ++n)
                    #pragma unroll
                    for (int j = 0; j < 4; ++j) {
                        int gr  = rowBase + wv * 16 + orow + j;
                        int col = h * 64 + n * 16 + lrow;
                        if (gr < N_NODES) Q[(size_t)gr * 128 + col] = acc[n][j];
                    }
            } else if (m == 1) {
                #pragma unroll
                for (int n = 0; n < 4; ++n) kreg[n] = acc[n];
            } else {
                #pragma unroll
                for (int n = 0; n < 4; ++n)
                    #pragma unroll
                    for (int j = 0; j < 4; ++j) {
                        int gr  = rowBase + wv * 16 + orow + j;
                        int col = h * 64 + n * 16 + lrow;
                        if (gr < N_NODES) {
                            unsigned p = f32_to_bf16_rne(kreg[n][j])
                                       | (f32_to_bf16_rne(acc[n][j]) << 16);
                            KV[(size_t)gr * 128 + col] = p;
                        }
                    }
            }
        }
    }
}

// ---------------------------------------------------------------------------
// CSR build: histogram -> exclusive scan -> scatter (stores COLS directly)
// ---------------------------------------------------------------------------
__global__ __launch_bounds__(256) void hist_kernel(
    const int* __restrict__ rows, int* __restrict__ counts)
{
    int e = blockIdx.x * 256 + threadIdx.x;
    if (e < E_EDGES) atomicAdd(&counts[rows[e]], 1);
}

__global__ __launch_bounds__(256) void scan1_kernel(
    const int* __restrict__ counts, int* __restrict__ starts,
    int* __restrict__ blockSums)
{
    __shared__ int s[256];
    int b = blockIdx.x, t = threadIdx.x;
    int base = b * SCAN_CHUNK + t * 4;
    int v0 = (base + 0 < N_NODES) ? counts[base + 0] : 0;
    int v1 = (base + 1 < N_NODES) ? counts[base + 1] : 0;
    int v2 = (base + 2 < N_NODES) ? counts[base + 2] : 0;
    int v3 = (base + 3 < N_NODES) ? counts[base + 3] : 0;
    int local = v0 + v1 + v2 + v3;
    s[t] = local;
    __syncthreads();
    for (int off = 1; off < 256; off <<= 1) {
        int x = (t >= off) ? s[t - off] : 0;
        __syncthreads();
        s[t] += x;
        __syncthreads();
    }
    int incl = s[t];
    int excl = incl - local;
    if (base + 0 < N_NODES) starts[base + 0] = excl;
    if (base + 1 < N_NODES) starts[base + 1] = excl + v0;
    if (base + 2 < N_NODES) starts[base + 2] = excl + v0 + v1;
    if (base + 3 < N_NODES) starts[base + 3] = excl + v0 + v1 + v2;
    if (t == 255) blockSums[b] = incl;
}

__global__ __launch_bounds__(128) void scan2_kernel(int* __restrict__ blockSums)
{
    __shared__ int s[128];
    int t = threadIdx.x;
    int v = (t < SCAN_NB) ? blockSums[t] : 0;
    s[t] = v;
    __syncthreads();
    for (int off = 1; off < 128; off <<= 1) {
        int x = (t >= off) ? s[t - off] : 0;
        __syncthreads();
        s[t] += x;
        __syncthreads();
    }
    if (t < SCAN_NB) blockSums[t] = s[t] - v;   // exclusive
}

__global__ __launch_bounds__(256) void scan3_kernel(
    int* __restrict__ starts, const int* __restrict__ blockSums,
    int* __restrict__ cursor)
{
    int i = blockIdx.x * 256 + threadIdx.x;
    if (i < N_NODES) {
        int v = starts[i] + blockSums[i >> 10];
        starts[i] = v;
        cursor[i] = v;
    }
}

__global__ __launch_bounds__(256) void scatter_kernel(
    const int* __restrict__ rows, const int* __restrict__ cols,
    int* __restrict__ cursor, int* __restrict__ csrCols)
{
    int e = blockIdx.x * 256 + threadIdx.x;
    if (e >= E_EDGES) return;
    int pos = atomicAdd(&cursor[rows[e]], 1);
    csrCols[pos] = cols[e];
}

// ---------------------------------------------------------------------------
// Kernel B: fused attention + aggregation, bf16-packed K/V, 2-edge unroll.
// ---------------------------------------------------------------------------
__global__ __launch_bounds__(256) void att_agg_kernel(
    const float* __restrict__ Q, const unsigned* __restrict__ KV,
    const float* __restrict__ filt,
    const int* __restrict__ starts, const int* __restrict__ counts,
    const int* __restrict__ csrCols,
    float* __restrict__ out)
{
    int t = threadIdx.x;
    int node = blockIdx.x * 2 + (t >> 7);
    if (node >= N_NODES) return;
    int d = t & 127;
    int h = d >> 5;

    float qd  = Q[(size_t)node * 128 + d];
    int   s   = starts[node];
    int   cnt = counts[node];

    float norm = 0.f, acc = 0.f;
    int i = 0;
    for (; i + 2 <= cnt; i += 2) {
        int c0 = csrCols[s + i];
        int c1 = csrCols[s + i + 1];
        unsigned kv0 = KV[(size_t)c0 * 128 + d];
        unsigned kv1 = KV[(size_t)c1 * 128 + d];
        float f0 = filt[(size_t)c0 * HEAD + h];
        float f1 = filt[(size_t)c1 * HEAD + h];
        float k0 = __uint_as_float(kv0 << 16);
        float v0 = __uint_as_float(kv0 & 0xffff0000u);
        float k1 = __uint_as_float(kv1 << 16);
        float v1 = __uint_as_float(kv1 & 0xffff0000u);

        float p0 = qd * k0;
        float p1 = qd * k1;
        p0 += __shfl_xor(p0, 1);   p1 += __shfl_xor(p1, 1);
        p0 += __shfl_xor(p0, 2);   p1 += __shfl_xor(p1, 2);
        p0 += __shfl_xor(p0, 4);   p1 += __shfl_xor(p1, 4);
        p0 += __shfl_xor(p0, 8);   p1 += __shfl_xor(p1, 8);
        p0 += __shfl_xor(p0, 16);  p1 += __shfl_xor(p1, 16);

        float w0 = __expf(fminf(fmaxf(p0, -10.f), 10.f) + f0);
        float w1 = __expf(fminf(fmaxf(p1, -10.f), 10.f) + f1);
        norm += w0 + w1;
        acc  += w0 * v0 + w1 * v1;
    }
    if (i < cnt) {
        int c0 = csrCols[s + i];
        unsigned kv0 = KV[(size_t)c0 * 128 + d];
        float f0 = filt[(size_t)c0 * HEAD + h];
        float k0 = __uint_as_float(kv0 << 16);
        float v0 = __uint_as_float(kv0 & 0xffff0000u);
        float p0 = qd * k0;
        p0 += __shfl_xor(p0, 1);
        p0 += __shfl_xor(p0, 2);
        p0 += __shfl_xor(p0, 4);
        p0 += __shfl_xor(p0, 8);
        p0 += __shfl_xor(p0, 16);
        float w0 = __expf(fminf(fmaxf(p0, -10.f), 10.f) + f0);
        norm += w0;
        acc  += w0 * v0;
    }
    out[(size_t)node * 128 + d] = acc / (norm + 1e-8f);
}

// ---------------------------------------------------------------------------
extern "C" void kernel_launch(void* const* d_in, const int* in_sizes, int n_in,
                              void* d_out, int out_size, void* d_ws, size_t ws_size,
                              hipStream_t stream) {
    const float* embeds = (const float*)d_in[0];
    const float* qT     = (const float*)d_in[1];
    const float* kT     = (const float*)d_in[2];
    const float* vT     = (const float*)d_in[3];
    const float* filt   = (const float*)d_in[4];
    const int*   rows   = (const int*)d_in[5];
    const int*   cols   = (const int*)d_in[6];
    float*       out    = (float*)d_out;

    // Workspace: Q: N*128 f32 | KV: N*128 u32 | counts,starts,cursor: N i32 |
    //            blockSums: 128 i32 | csrCols: E i32
    float*    Q  = (float*)d_ws;
    unsigned* KV = (unsigned*)(Q + (size_t)N_NODES * 128);
    int* counts    = (int*)(KV + (size_t)N_NODES * 128);
    int* starts    = counts + N_NODES;
    int* cursor    = starts + N_NODES;
    int* blockSums = cursor + N_NODES;
    int* csrCols   = blockSums + 128;

    // Split-bf16 weight planes ALIAS the csrCols region (192 KiB of 2.34 MiB).
    // Stream-ordered safe: wprep+qkv complete before scatter writes csrCols.
    unsigned short* WThi = (unsigned short*)csrCols;          // 96 KiB
    unsigned short* WTlo = WThi + 3 * 128 * 128;              // 96 KiB

    hipMemsetAsync(counts, 0, sizeof(int) * N_NODES, stream);

    wprep_kernel<<<12, 256, 0, stream>>>(qT, kT, vT, WThi, WTlo);
    qkv_mfma_kernel<<<(N_NODES + 63) / 64, 256, 0, stream>>>(embeds, WThi, WTlo, Q, KV);

    hist_kernel<<<(E_EDGES + 255) / 256, 256, 0, stream>>>(rows, counts);
    scan1_kernel<<<SCAN_NB, 256, 0, stream>>>(counts, starts, blockSums);
    scan2_kernel<<<1, 128, 0, stream>>>(blockSums);
    scan3_kernel<<<(N_NODES + 255) / 256, 256, 0, stream>>>(starts, blockSums, cursor);
    scatter_kernel<<<(E_EDGES + 255) / 256, 256, 0, stream>>>(rows, cols, cursor, csrCols);

    att_agg_kernel<<<(N_NODES + 1) / 2, 256, 0, stream>>>(
        Q, KV, filt, starts, counts, csrCols, out);
}

// Round 2
// 291.198 us; speedup vs baseline: 1.5172x; 1.1542x over previous
//
#include <hip/hip_runtime.h>

#define N_NODES 100000
#define E_EDGES 600000
#define LATDIM 128
#define HEAD 4
#define HDIM 32

#define SCAN_CHUNK 1024
#define SCAN_NB ((N_NODES + SCAN_CHUNK - 1) / SCAN_CHUNK)   // 98

typedef __bf16 bf16x8 __attribute__((ext_vector_type(8)));
typedef float  f32x4  __attribute__((ext_vector_type(4)));

__device__ __forceinline__ unsigned f32_to_bf16_rne(float x) {
    unsigned u = __float_as_uint(x);
    u += 0x7fffu + ((u >> 16) & 1u);   // round to nearest even
    return u >> 16;
}

__device__ __forceinline__ void bf16_split(float x, unsigned& hi, unsigned& lo) {
    unsigned hb = f32_to_bf16_rne(x);
    float hf = __uint_as_float(hb << 16);
    unsigned lb = f32_to_bf16_rne(x - hf);
    hi = hb; lo = lb;
}

// ---------------------------------------------------------------------------
// Weight prep: W[k][c] f32 -> WT_hi/WT_lo[m][c][k] bf16 (split precision).
// ---------------------------------------------------------------------------
__global__ __launch_bounds__(256) void wprep_kernel(
    const float* __restrict__ qT, const float* __restrict__ kT,
    const float* __restrict__ vT,
    unsigned short* __restrict__ WThi, unsigned short* __restrict__ WTlo)
{
    int g = blockIdx.x * 256 + threadIdx.x;      // 0..3071
    if (g >= 3072) return;
    int m    = g >> 10;          // 0..2
    int rem  = g & 1023;
    int c    = rem >> 3;         // 0..127
    int k0   = (rem & 7) * 16;   // 0..112
    const float* W = (m == 0) ? qT : (m == 1) ? kT : vT;

    unsigned short hi[16], lo[16];
    #pragma unroll
    for (int j = 0; j < 16; ++j) {
        float x = W[(size_t)(k0 + j) * 128 + c];
        unsigned hb, lb;
        bf16_split(x, hb, lb);
        hi[j] = (unsigned short)hb;
        lo[j] = (unsigned short)lb;
    }
    size_t off = (size_t)m * 16384 + (size_t)c * 128 + k0;
    *(uint4*)(WThi + off)     = *(const uint4*)&hi[0];
    *(uint4*)(WThi + off + 8) = *(const uint4*)&hi[8];
    *(uint4*)(WTlo + off)     = *(const uint4*)&lo[0];
    *(uint4*)(WTlo + off + 8) = *(const uint4*)&lo[8];
}

// ---------------------------------------------------------------------------
// Kernel A (MFMA): fused per-node Q/K/V transform via 16x16x32 bf16 MFMA with
// split-precision (hi+lo) operands: a*b ~= ah*bh + al*bh + ah*bl  (fp32-level).
// ---------------------------------------------------------------------------
__global__ __launch_bounds__(256, 2) void qkv_mfma_kernel(
    const float* __restrict__ embeds,
    const unsigned short* __restrict__ WThi,
    const unsigned short* __restrict__ WTlo,
    float* __restrict__ Q, unsigned* __restrict__ KV)
{
    __shared__ __align__(16) char smem[65536];
    char* Ahi = smem;              // 16 KiB: 64 rows x 256B
    char* Alo = smem + 16384;
    char* Bhi = smem + 32768;      // 16 KiB: 64 cols x 256B
    char* Blo = smem + 49152;

    const int tid = threadIdx.x;
    const int rowBase = blockIdx.x * 64;

    // ---- stage A: load embeds f32, split to bf16 hi/lo, swizzled LDS ----
    #pragma unroll
    for (int it = 0; it < 8; ++it) {
        int idx = it * 256 + tid;          // 0..2047 float4 chunks
        int r  = idx >> 5;                 // 0..63
        int c4 = idx & 31;                 // 0..31
        int gr = rowBase + r;
        float4 v = make_float4(0.f, 0.f, 0.f, 0.f);
        if (gr < N_NODES) v = ((const float4*)embeds)[(size_t)gr * 32 + c4];
        unsigned hx, lx, hy, ly, hz, lz, hw, lw;
        bf16_split(v.x, hx, lx); bf16_split(v.y, hy, ly);
        bf16_split(v.z, hz, lz); bf16_split(v.w, hw, lw);
        uint2 hp = make_uint2(hx | (hy << 16), hz | (hw << 16));
        uint2 lp = make_uint2(lx | (ly << 16), lz | (lw << 16));
        int byte = r * 256 + c4 * 8;
        int swz  = byte ^ ((r & 7) << 4);
        *(uint2*)(Ahi + swz) = hp;
        *(uint2*)(Alo + swz) = lp;
    }
    __syncthreads();

    const int lane = tid & 63;
    const int wv   = tid >> 6;         // 0..3 (wave -> 16-row tile)
    const int lrow = lane & 15;
    const int kg   = lane >> 4;        // 0..3 (k-group of MFMA operand)
    const int arow = wv * 16 + lrow;   // 0..63

    // ---- hoisted A fragments (reused for all 6 (h,m) output panels) ----
    bf16x8 a_hi[4], a_lo[4];
    #pragma unroll
    for (int kk = 0; kk < 4; ++kk) {
        int byte = arow * 256 + kk * 64 + kg * 16;
        int swz  = byte ^ ((lrow & 7) << 4);     // (arow&7)==(lrow&7)
        a_hi[kk] = __builtin_bit_cast(bf16x8, *(const uint4*)(Ahi + swz));
        a_lo[kk] = __builtin_bit_cast(bf16x8, *(const uint4*)(Alo + swz));
    }

    const int orow = kg << 2;   // C/D row base within 16-row tile (m89 layout)

    for (int h = 0; h < 2; ++h) {          // column half: cols h*64..h*64+63
        f32x4 kreg[4];
        for (int m = 0; m < 3; ++m) {      // 0:Q 1:K 2:V
            __syncthreads();               // prev panel's B reads done
            // ---- stage B(m,h): 64 cols x 128 k, hi+lo, swizzled copy ----
            {
                const char* srch = (const char*)(WThi + (size_t)m * 16384 + (size_t)h * 8192);
                const char* srcl = (const char*)(WTlo + (size_t)m * 16384 + (size_t)h * 8192);
                #pragma unroll
                for (int it = 0; it < 4; ++it) {
                    int idx  = it * 256 + tid;         // 16B chunk id, 0..1023
                    int cl   = idx >> 4;               // col 0..63
                    int byte = idx * 16;               // == cl*256 + ch*16
                    int swz  = (cl * 256 + (idx & 15) * 16) ^ ((cl & 7) << 4);
                    *(uint4*)(Bhi + swz) = *(const uint4*)(srch + byte);
                    *(uint4*)(Blo + swz) = *(const uint4*)(srcl + byte);
                }
            }
            __syncthreads();

            f32x4 acc[4] = { {0.f,0.f,0.f,0.f}, {0.f,0.f,0.f,0.f},
                             {0.f,0.f,0.f,0.f}, {0.f,0.f,0.f,0.f} };
            #pragma unroll
            for (int kk = 0; kk < 4; ++kk) {
                #pragma unroll
                for (int n = 0; n < 4; ++n) {
                    int brow = n * 16 + lrow;
                    int byte = brow * 256 + kk * 64 + kg * 16;
                    int swz  = byte ^ ((lrow & 7) << 4);   // (brow&7)==(lrow&7)
                    bf16x8 bh = __builtin_bit_cast(bf16x8, *(const uint4*)(Bhi + swz));
                    bf16x8 bl = __builtin_bit_cast(bf16x8, *(const uint4*)(Blo + swz));
                    acc[n] = __builtin_amdgcn_mfma_f32_16x16x32_bf16(a_hi[kk], bh, acc[n], 0, 0, 0);
                    acc[n] = __builtin_amdgcn_mfma_f32_16x16x32_bf16(a_lo[kk], bh, acc[n], 0, 0, 0);
                    acc[n] = __builtin_amdgcn_mfma_f32_16x16x32_bf16(a_hi[kk], bl, acc[n], 0, 0, 0);
                }
            }

            if (m == 0) {
                #pragma unroll
                for (int n = 0; n < 4; ++n)
                    #pragma unroll
                    for (int j = 0; j < 4; ++j) {
                        int gr  = rowBase + wv * 16 + orow + j;
                        int col = h * 64 + n * 16 + lrow;
                        if (gr < N_NODES) Q[(size_t)gr * 128 + col] = acc[n][j];
                    }
            } else if (m == 1) {
                #pragma unroll
                for (int n = 0; n < 4; ++n) kreg[n] = acc[n];
            } else {
                #pragma unroll
                for (int n = 0; n < 4; ++n)
                    #pragma unroll
                    for (int j = 0; j < 4; ++j) {
                        int gr  = rowBase + wv * 16 + orow + j;
                        int col = h * 64 + n * 16 + lrow;
                        if (gr < N_NODES) {
                            unsigned p = f32_to_bf16_rne(kreg[n][j])
                                       | (f32_to_bf16_rne(acc[n][j]) << 16);
                            KV[(size_t)gr * 128 + col] = p;
                        }
                    }
            }
        }
    }
}

// ---------------------------------------------------------------------------
// CSR build: histogram -> exclusive scan -> scatter (stores COLS directly)
// ---------------------------------------------------------------------------
__global__ __launch_bounds__(256) void hist_kernel(
    const int* __restrict__ rows, int* __restrict__ counts)
{
    int e = blockIdx.x * 256 + threadIdx.x;
    if (e < E_EDGES) atomicAdd(&counts[rows[e]], 1);
}

__global__ __launch_bounds__(256) void scan1_kernel(
    const int* __restrict__ counts, int* __restrict__ starts,
    int* __restrict__ blockSums)
{
    __shared__ int s[256];
    int b = blockIdx.x, t = threadIdx.x;
    int base = b * SCAN_CHUNK + t * 4;
    int v0 = (base + 0 < N_NODES) ? counts[base + 0] : 0;
    int v1 = (base + 1 < N_NODES) ? counts[base + 1] : 0;
    int v2 = (base + 2 < N_NODES) ? counts[base + 2] : 0;
    int v3 = (base + 3 < N_NODES) ? counts[base + 3] : 0;
    int local = v0 + v1 + v2 + v3;
    s[t] = local;
    __syncthreads();
    for (int off = 1; off < 256; off <<= 1) {
        int x = (t >= off) ? s[t - off] : 0;
        __syncthreads();
        s[t] += x;
        __syncthreads();
    }
    int incl = s[t];
    int excl = incl - local;
    if (base + 0 < N_NODES) starts[base + 0] = excl;
    if (base + 1 < N_NODES) starts[base + 1] = excl + v0;
    if (base + 2 < N_NODES) starts[base + 2] = excl + v0 + v1;
    if (base + 3 < N_NODES) starts[base + 3] = excl + v0 + v1 + v2;
    if (t == 255) blockSums[b] = incl;
}

__global__ __launch_bounds__(128) void scan2_kernel(int* __restrict__ blockSums)
{
    __shared__ int s[128];
    int t = threadIdx.x;
    int v = (t < SCAN_NB) ? blockSums[t] : 0;
    s[t] = v;
    __syncthreads();
    for (int off = 1; off < 128; off <<= 1) {
        int x = (t >= off) ? s[t - off] : 0;
        __syncthreads();
        s[t] += x;
        __syncthreads();
    }
    if (t < SCAN_NB) blockSums[t] = s[t] - v;   // exclusive
}

__global__ __launch_bounds__(256) void scan3_kernel(
    int* __restrict__ starts, const int* __restrict__ blockSums,
    int* __restrict__ cursor)
{
    int i = blockIdx.x * 256 + threadIdx.x;
    if (i < N_NODES) {
        int v = starts[i] + blockSums[i >> 10];
        starts[i] = v;
        cursor[i] = v;
    }
}

__global__ __launch_bounds__(256) void scatter_kernel(
    const int* __restrict__ rows, const int* __restrict__ cols,
    int* __restrict__ cursor, int* __restrict__ csrCols)
{
    int e = blockIdx.x * 256 + threadIdx.x;
    if (e >= E_EDGES) return;
    int pos = atomicAdd(&cursor[rows[e]], 1);
    csrCols[pos] = cols[e];
}

// ---------------------------------------------------------------------------
// Kernel B: fused attention + aggregation.
// NEW: 32 threads/node, 4 dims/thread (uint4 KV load = 16B/lane).
// Head-reduce = 3 shfl_xor over the 8-lane head group (was 5 over 32).
// 8 nodes per 256-thr block; 2 edges per wave in flight; 2-edge unroll.
// ---------------------------------------------------------------------------
__global__ __launch_bounds__(256) void att_agg_kernel(
    const float* __restrict__ Q, const unsigned* __restrict__ KV,
    const float* __restrict__ filt,
    const int* __restrict__ starts, const int* __restrict__ counts,
    const int* __restrict__ csrCols,
    float* __restrict__ out)
{
    int t = threadIdx.x;
    int node = blockIdx.x * 8 + (t >> 5);
    if (node >= N_NODES) return;
    int lane = t & 31;           // lane within node group
    int h = lane >> 3;           // head = (lane*4)>>5

    float4 q = ((const float4*)(Q + (size_t)node * 128))[lane];
    int s   = starts[node];
    int cnt = counts[node];

    float norm = 0.f;
    float ax = 0.f, ay = 0.f, az = 0.f, aw = 0.f;

    int i = 0;
    for (; i + 2 <= cnt; i += 2) {
        int c0 = csrCols[s + i];
        int c1 = csrCols[s + i + 1];
        uint4 kv0 = ((const uint4*)KV)[(size_t)c0 * 32 + lane];
        uint4 kv1 = ((const uint4*)KV)[(size_t)c1 * 32 + lane];
        float f0 = filt[c0 * HEAD + h];
        float f1 = filt[c1 * HEAD + h];

        float k0x = __uint_as_float(kv0.x << 16), v0x = __uint_as_float(kv0.x & 0xffff0000u);
        float k0y = __uint_as_float(kv0.y << 16), v0y = __uint_as_float(kv0.y & 0xffff0000u);
        float k0z = __uint_as_float(kv0.z << 16), v0z = __uint_as_float(kv0.z & 0xffff0000u);
        float k0w = __uint_as_float(kv0.w << 16), v0w = __uint_as_float(kv0.w & 0xffff0000u);
        float k1x = __uint_as_float(kv1.x << 16), v1x = __uint_as_float(kv1.x & 0xffff0000u);
        float k1y = __uint_as_float(kv1.y << 16), v1y = __uint_as_float(kv1.y & 0xffff0000u);
        float k1z = __uint_as_float(kv1.z << 16), v1z = __uint_as_float(kv1.z & 0xffff0000u);
        float k1w = __uint_as_float(kv1.w << 16), v1w = __uint_as_float(kv1.w & 0xffff0000u);

        float p0 = q.x * k0x + q.y * k0y + q.z * k0z + q.w * k0w;
        float p1 = q.x * k1x + q.y * k1y + q.z * k1z + q.w * k1w;
        p0 += __shfl_xor(p0, 1);   p1 += __shfl_xor(p1, 1);
        p0 += __shfl_xor(p0, 2);   p1 += __shfl_xor(p1, 2);
        p0 += __shfl_xor(p0, 4);   p1 += __shfl_xor(p1, 4);

        float w0 = __expf(fminf(fmaxf(p0, -10.f), 10.f) + f0);
        float w1 = __expf(fminf(fmaxf(p1, -10.f), 10.f) + f1);
        norm += w0 + w1;
        ax += w0 * v0x + w1 * v1x;
        ay += w0 * v0y + w1 * v1y;
        az += w0 * v0z + w1 * v1z;
        aw += w0 * v0w + w1 * v1w;
    }
    if (i < cnt) {
        int c0 = csrCols[s + i];
        uint4 kv0 = ((const uint4*)KV)[(size_t)c0 * 32 + lane];
        float f0 = filt[c0 * HEAD + h];
        float k0x = __uint_as_float(kv0.x << 16), v0x = __uint_as_float(kv0.x & 0xffff0000u);
        float k0y = __uint_as_float(kv0.y << 16), v0y = __uint_as_float(kv0.y & 0xffff0000u);
        float k0z = __uint_as_float(kv0.z << 16), v0z = __uint_as_float(kv0.z & 0xffff0000u);
        float k0w = __uint_as_float(kv0.w << 16), v0w = __uint_as_float(kv0.w & 0xffff0000u);
        float p0 = q.x * k0x + q.y * k0y + q.z * k0z + q.w * k0w;
        p0 += __shfl_xor(p0, 1);
        p0 += __shfl_xor(p0, 2);
        p0 += __shfl_xor(p0, 4);
        float w0 = __expf(fminf(fmaxf(p0, -10.f), 10.f) + f0);
        norm += w0;
        ax += w0 * v0x; ay += w0 * v0y; az += w0 * v0z; aw += w0 * v0w;
    }
    float inv = 1.0f / (norm + 1e-8f);
    ((float4*)(out + (size_t)node * 128))[lane] =
        make_float4(ax * inv, ay * inv, az * inv, aw * inv);
}

// ---------------------------------------------------------------------------
extern "C" void kernel_launch(void* const* d_in, const int* in_sizes, int n_in,
                              void* d_out, int out_size, void* d_ws, size_t ws_size,
                              hipStream_t stream) {
    const float* embeds = (const float*)d_in[0];
    const float* qT     = (const float*)d_in[1];
    const float* kT     = (const float*)d_in[2];
    const float* vT     = (const float*)d_in[3];
    const float* filt   = (const float*)d_in[4];
    const int*   rows   = (const int*)d_in[5];
    const int*   cols   = (const int*)d_in[6];
    float*       out    = (float*)d_out;

    // Workspace: Q: N*128 f32 | KV: N*128 u32 | counts,starts,cursor: N i32 |
    //            blockSums: 128 i32 | csrCols: E i32
    float*    Q  = (float*)d_ws;
    unsigned* KV = (unsigned*)(Q + (size_t)N_NODES * 128);
    int* counts    = (int*)(KV + (size_t)N_NODES * 128);
    int* starts    = counts + N_NODES;
    int* cursor    = starts + N_NODES;
    int* blockSums = cursor + N_NODES;
    int* csrCols   = blockSums + 128;

    // Split-bf16 weight planes ALIAS the csrCols region (192 KiB of 2.34 MiB).
    // Stream-ordered safe: wprep+qkv complete before scatter writes csrCols.
    unsigned short* WThi = (unsigned short*)csrCols;          // 96 KiB
    unsigned short* WTlo = WThi + 3 * 128 * 128;              // 96 KiB

    hipMemsetAsync(counts, 0, sizeof(int) * N_NODES, stream);

    wprep_kernel<<<12, 256, 0, stream>>>(qT, kT, vT, WThi, WTlo);
    qkv_mfma_kernel<<<(N_NODES + 63) / 64, 256, 0, stream>>>(embeds, WThi, WTlo, Q, KV);

    hist_kernel<<<(E_EDGES + 255) / 256, 256, 0, stream>>>(rows, counts);
    scan1_kernel<<<SCAN_NB, 256, 0, stream>>>(counts, starts, blockSums);
    scan2_kernel<<<1, 128, 0, stream>>>(blockSums);
    scan3_kernel<<<(N_NODES + 255) / 256, 256, 0, stream>>>(starts, blockSums, cursor);
    scatter_kernel<<<(E_EDGES + 255) / 256, 256, 0, stream>>>(rows, cols, cursor, csrCols);

    att_agg_kernel<<<(N_NODES + 7) / 8, 256, 0, stream>>>(
        Q, KV, filt, starts, counts, csrCols, out);
}